// Round 11
// baseline (196.976 us; speedup 1.0000x reference)
//
#include <hip/hip_runtime.h>
#include <cstdint>

// Moment-expansion cross-attention (rank-1 logits), T=48 Taylor, all f32.
//   x_ij = c_i*kx_j, c_i=(Ah*qx_i+Bkh)/8, c'=c*S_b, khat=kx/S_b
//   out = [sum_t (c'^t/t!) PW_t] / [sum_t (c'^t/t!) zeta_t] + bv
// ws (floats, 256 MiB total proven by fill counter):
//   [0..3] S_b | [4..19] Ah | [20..35] Bkh | [64..255] zco[b][48]
//   WS_P   = 1024:     P[b][t][c]    196608
//   WS_PW  = 197632:   PW[b][t][hd]  196608
//   WS_CZ  = 394240:   cz[(h*4+b)*2048+i]{c',rZ} 262144
//   WS_PART= 1048576:  mom partials [b][jc64][t][c] 12582912 (50.3 MB)
//   WS_PP  = 14680064: proj partials [cc][b][t][hd] 3145728 (12.6 MB)
// d_out written only by k_out.

#define WS_P    1024
#define WS_PW   197632
#define WS_CZ   394240
#define WS_PART 1048576
#define WS_PP   14680064
#define MOM_JC  32

// ---- k_prep: per-b S_b=max|kx|, zco[b][t]=sum_j khat^t; Ah/Bkh per head ----
__global__ __launch_bounds__(256, 1) void k_prep(const float* __restrict__ key,
                                                 const float* __restrict__ Wq,
                                                 const float* __restrict__ bq,
                                                 const float* __restrict__ Wk,
                                                 float* __restrict__ ws) {
  __shared__ float kxl[2048];
  __shared__ float wmax[4];
  __shared__ float wz[4][48];
  int t = threadIdx.x, l = t & 63, w = t >> 6;
  int b = blockIdx.x;
  float m = 0.f;
  for (int j = t; j < 2048; j += 256) {
    float v = key[b * 2048 + j];
    kxl[j] = v;
    m = fmaxf(m, fabsf(v));
  }
  for (int off = 32; off; off >>= 1) m = fmaxf(m, __shfl_xor(m, off));
  if (l == 0) wmax[w] = m;
  __syncthreads();
  float S = fmaxf(fmaxf(wmax[0], wmax[1]), fmaxf(wmax[2], wmax[3]));
  if (t == 0) ws[b] = S;
  float rs = 1.0f / S;

  float z[48];
#pragma unroll
  for (int q = 0; q < 48; ++q) z[q] = 0.f;
  for (int jj = 0; jj < 8; ++jj) {
    float kh = kxl[t * 8 + jj] * rs;
    float p = 1.f;
#pragma unroll
    for (int q = 0; q < 48; ++q) { z[q] += p; p *= kh; }
  }
#pragma unroll
  for (int q = 0; q < 48; ++q) {
    float v = z[q];
    for (int off = 32; off; off >>= 1) v += __shfl_xor(v, off);
    if (l == 0) wz[w][q] = v;
  }
  __syncthreads();
  if (t < 48) ws[64 + b * 48 + t] = wz[0][t] + wz[1][t] + wz[2][t] + wz[3][t];

  if (b == 0 && t < 32) {           // Ah (t<16) / Bkh (t>=16)
    int h = t & 15; bool isB = t >= 16;
    float a = 0.f;
    for (int d = 0; d < 64; ++d)
      a = fmaf(isB ? bq[h * 64 + d] : Wq[h * 64 + d], Wk[h * 64 + d], a);
    ws[4 + (isB ? 16 : 0) + h] = a;
  }
}

// ---- k_mom: part[b][jc][t][c] = sum_{j in 32-chunk} khat^t * value[b,j,c] ----
// LDS value tile (32 KB) + 3 t-passes of acc[16]: spill-proof by construction.
// grid (4 ct, 64 jc, 4 b) = 1024 blocks, ~4/CU.
__global__ __launch_bounds__(256, 1) void k_mom(const float* __restrict__ value,
                                                const float* __restrict__ key,
                                                const float* __restrict__ ws,
                                                float* __restrict__ wsout) {
  __shared__ float tile[MOM_JC * 256];   // [j][c] row-major, 32 KB
  __shared__ float khl[MOM_JC];
  __shared__ float khb[2 * MOM_JC];      // kh^16 | kh^32
  int tid = threadIdx.x;
  int ct = blockIdx.x, jc = blockIdx.y, b = blockIdx.z;
  int c0 = ct * 256, j0 = jc * MOM_JC;
  float rs = 1.0f / ws[b];
  if (tid < MOM_JC) {
    float kh = key[b * 2048 + j0 + tid] * rs;
    khl[tid] = kh;
    float kh2 = kh * kh, kh4 = kh2 * kh2, kh8 = kh4 * kh4;
    float kh16 = kh8 * kh8;
    khb[tid] = kh16;
    khb[MOM_JC + tid] = kh16 * kh16;
  }
  {
    const float* vsrc = value + (((size_t)(b * 2048 + j0)) << 10) + c0;
    int x = tid * 4;
#pragma unroll
    for (int p = 0; p < (MOM_JC * 256) / 1024; ++p) {
      int idx = p * 1024 + x;
      int row = idx >> 8, col = idx & 255;
      *reinterpret_cast<float4*>(&tile[idx]) =
          *reinterpret_cast<const float4*>(&vsrc[((size_t)row << 10) + col]);
    }
  }
  __syncthreads();

  size_t pb0 = WS_PART + (((size_t)((b * 64 + jc) * 48)) << 10) + c0 + tid;
#pragma unroll
  for (int tc = 0; tc < 3; ++tc) {
    float acc[16];
#pragma unroll
    for (int a = 0; a < 16; ++a) acc[a] = 0.f;
    for (int j = 0; j < MOM_JC; j += 4) {
      float4 khq = *reinterpret_cast<const float4*>(&khl[j]);
      float4 bq4 = (tc == 0) ? make_float4(1.f, 1.f, 1.f, 1.f)
                             : *reinterpret_cast<const float4*>(&khb[(tc - 1) * MOM_JC + j]);
#pragma unroll
      for (int u = 0; u < 4; ++u) {
        float v = tile[(j + u) * 256 + tid];
        float kh = reinterpret_cast<const float*>(&khq)[u];
        float base = reinterpret_cast<const float*>(&bq4)[u];
        float kh2 = kh * kh;
        float k4 = kh2 * kh2;
        float q0 = base, q1 = base * kh, q2 = base * kh2, q3 = q2 * kh;
#pragma unroll
        for (int g = 0; g < 4; ++g) {
          acc[4 * g + 0] = fmaf(q0, v, acc[4 * g + 0]);
          acc[4 * g + 1] = fmaf(q1, v, acc[4 * g + 1]);
          acc[4 * g + 2] = fmaf(q2, v, acc[4 * g + 2]);
          acc[4 * g + 3] = fmaf(q3, v, acc[4 * g + 3]);
          if (g < 3) { q0 *= k4; q1 *= k4; q2 *= k4; q3 *= k4; }
        }
      }
    }
#pragma unroll
    for (int a = 0; a < 16; ++a)
      wsout[pb0 + (((size_t)(tc * 16 + a)) << 10)] = acc[a];
  }
}

// ---- k_red: P[b][t][c] = sum_jc part ----
__global__ __launch_bounds__(256, 1) void k_red(float* __restrict__ ws) {
  int gid = blockIdx.x * 256 + threadIdx.x;     // < 196608
  int c = gid & 1023; int bt = gid >> 10; int t = bt % 48; int b = bt / 48;
  float s = 0.f;
  for (int jc = 0; jc < 64; ++jc)
    s += ws[WS_PART + (((size_t)((b * 64 + jc) * 48 + t)) << 10) + c];
  ws[WS_P + (((size_t)(b * 48 + t)) << 10) + c] = s;
}

// ---- k_proj: pp[cc][b][t][hd] = sum_{c in 64-chunk} P[b][t][c]*Wv[c][hd] ----
// grid (16 cc, 4 hdt, 12 = 4b*3tt). acc[16]: no spill (proven round 10).
__global__ __launch_bounds__(256, 1) void k_proj(const float* __restrict__ wsin,
                                                 const float* __restrict__ Wv,
                                                 float* __restrict__ ws) {
  __shared__ float Pl[16 * 64];
  int tid = threadIdx.x;
  int cc = blockIdx.x, hdt = blockIdx.y;
  int b = blockIdx.z & 3, tt = blockIdx.z >> 2;
  int hd = hdt * 256 + tid;
  for (int x = tid; x < 16 * 64; x += 256) {
    int q = x >> 6, cl = x & 63;
    Pl[x] = wsin[WS_P + (((size_t)(b * 48 + tt * 16 + q)) << 10) + cc * 64 + cl];
  }
  __syncthreads();
  float acc[16];
#pragma unroll
  for (int q = 0; q < 16; ++q) acc[q] = 0.f;
  for (int c = 0; c < 64; ++c) {
    float wv = Wv[(((size_t)(cc * 64 + c)) << 10) + hd];
#pragma unroll
    for (int q = 0; q < 16; ++q)
      acc[q] = fmaf(Pl[(q << 6) + c], wv, acc[q]);
  }
  size_t base = WS_PP + (((size_t)((cc * 4 + b) * 48 + tt * 16)) << 10) + hd;
#pragma unroll
  for (int q = 0; q < 16; ++q) ws[base + (((size_t)q) << 10)] = acc[q];
}

// ---- k_projred: PW[b][t][hd] = sum_cc pp ----
__global__ __launch_bounds__(256, 1) void k_projred(float* __restrict__ ws) {
  int gid = blockIdx.x * 256 + threadIdx.x;     // < 196608
  int hd = gid & 1023; int bt = gid >> 10; int t = bt % 48; int b = bt / 48;
  float s = 0.f;
  for (int cc = 0; cc < 16; ++cc)
    s += ws[WS_PP + (((size_t)((cc * 4 + b) * 48 + t)) << 10) + hd];
  ws[WS_PW + (((size_t)(b * 48 + t)) << 10) + hd] = s;
}

// ---- k_z: per (h,b,i): c' and 1/Z via nested Horner over zco ----
__global__ __launch_bounds__(256, 1) void k_z(const float* __restrict__ query,
                                              float* __restrict__ ws) {
  int bid = blockIdx.x;                 // 512
  int h = bid >> 5; int b = (bid >> 3) & 3; int it = bid & 7;
  int i = it * 256 + threadIdx.x;
  float S = ws[b];
  float Ah = ws[4 + h], Bkh = ws[20 + h];
  float qx = query[b * 2048 + i];
  float cp = fmaf(Ah, qx, Bkh) * 0.125f * S;
  const float* zc = ws + 64 + b * 48;
  float r = zc[47];
#pragma unroll
  for (int t = 47; t >= 1; --t)
    r = fmaf(cp * (1.0f / (float)t), r, zc[t - 1]);
  float rz = 1.0f / r;
  size_t o = ((size_t)((h * 4 + b) * 2048 + i)) * 2;
  ws[WS_CZ + o] = cp;
  ws[WS_CZ + o + 1] = rz;
}

// ---- k_out: out[(h*4+b), i, d] = Horner(PW)/Z + bv ----
__global__ __launch_bounds__(256, 1) void k_out(const float* __restrict__ ws,
                                                const float* __restrict__ bv,
                                                float* __restrict__ out) {
  int tid = threadIdx.x; int l = tid & 63; int w = tid >> 6;
  int qt = blockIdx.x, b = blockIdx.y, h = blockIdx.z;
  float a[48];
  const float* PW = ws + WS_PW + (((size_t)(b * 48)) << 10) + h * 64 + l;
#pragma unroll
  for (int q = 0; q < 48; ++q) a[q] = PW[((size_t)q) << 10];
  float bvd = bv[h * 64 + l];
  const float* cz = ws + WS_CZ + ((size_t)((h * 4 + b) * 2048 + qt * 256 + w * 64)) * 2;
  size_t ob = ((((size_t)((h * 4 + b) * 2048)) + qt * 256 + w * 64) << 6) + l;
  for (int r = 0; r < 64; ++r) {
    float cp = cz[r * 2], rz = cz[r * 2 + 1];
    float acc = a[47];
#pragma unroll
    for (int t = 47; t >= 1; --t)
      acc = fmaf(cp * (1.0f / (float)t), acc, a[t - 1]);
    out[ob + (((size_t)r) << 6)] = fmaf(acc, rz, bvd);
  }
}

extern "C" void kernel_launch(void* const* d_in, const int* in_sizes, int n_in,
                              void* d_out, int out_size, void* d_ws, size_t ws_size,
                              hipStream_t stream) {
  const float* query = (const float*)d_in[0];
  const float* key   = (const float*)d_in[1];
  const float* value = (const float*)d_in[2];
  const float* Wq    = (const float*)d_in[3];
  const float* bq    = (const float*)d_in[4];
  const float* Wk    = (const float*)d_in[5];
  // bk = d_in[6] cancels in softmax
  const float* Wv    = (const float*)d_in[7];
  const float* bv    = (const float*)d_in[8];
  float* out = (float*)d_out;
  float* ws  = (float*)d_ws;

  k_prep<<<dim3(4), 256, 0, stream>>>(key, Wq, bq, Wk, ws);
  k_mom<<<dim3(4, 64, 4), 256, 0, stream>>>(value, key, ws, ws);
  k_red<<<dim3(768), 256, 0, stream>>>(ws);
  k_proj<<<dim3(16, 4, 12), 256, 0, stream>>>(ws, Wv, ws);
  k_projred<<<dim3(768), 256, 0, stream>>>(ws);
  k_z<<<dim3(512), 256, 0, stream>>>(query, ws);
  k_out<<<dim3(8, 4, 16), 256, 0, stream>>>(ws, bv, out);
}